// Round 1
// baseline (3643.801 us; speedup 1.0000x reference)
//
#include <hip/hip_runtime.h>
#include <math.h>

// ---------------------------------------------------------------------------
// CapsNet forward, fp32 everywhere (no fp32 MFMA on CDNA4 -> vector ALU).
// Pipeline: conv1+relu -> prim conv (K-split x4) -> squash -> routing ->
// classes/argmax -> decoder (3 layers) -> sigmoid.
// ---------------------------------------------------------------------------

// ======================= conv1: [B,1,28,28] -> [B,256,20,20] relu ==========
__global__ __launch_bounds__(256) void k_conv1(const float* __restrict__ x,
                                               const float* __restrict__ w,
                                               const float* __restrict__ bias,
                                               float* __restrict__ h) {
  const int bid = blockIdx.x;
  const int img = bid >> 2, ocq = bid & 3;          // 64 oc per block
  __shared__ float xs[784];
  __shared__ float ws[64 * 81];
  const int t = threadIdx.x;
  const float4* xg = (const float4*)(x + (size_t)img * 784);
  if (t < 196) ((float4*)xs)[t] = xg[t];
  const float4* wg = (const float4*)(w + (size_t)ocq * 64 * 81);
  for (int i = t; i < 1296; i += 256) ((float4*)ws)[i] = wg[i];
  __syncthreads();
  const int ocl = t & 63, rowg = t >> 6;            // wave-uniform row
  const int oc = ocq * 64 + ocl;
  const float bv = bias[oc];
  float* hb = h + ((size_t)img * 256 + oc) * 400;
#pragma unroll 1
  for (int r = rowg; r < 20; r += 4) {
    float acc[20];
#pragma unroll
    for (int p = 0; p < 20; p++) acc[p] = bv;
#pragma unroll
    for (int ky = 0; ky < 9; ky++) {
      float xr[28];
      const float* xrow = &xs[(r + ky) * 28];       // broadcast reads (free)
#pragma unroll
      for (int q = 0; q < 7; q++) ((float4*)xr)[q] = ((const float4*)xrow)[q];
      float wr[9];
#pragma unroll
      for (int i = 0; i < 9; i++) wr[i] = ws[ocl * 81 + ky * 9 + i];
#pragma unroll
      for (int kx = 0; kx < 9; kx++)
#pragma unroll
        for (int p = 0; p < 20; p++)
          acc[p] = fmaf(wr[kx], xr[p + kx], acc[p]);
    }
#pragma unroll
    for (int p = 0; p < 20; p++) acc[p] = fmaxf(acc[p], 0.f);
#pragma unroll
    for (int q = 0; q < 5; q++) ((float4*)(hb + r * 20))[q] = ((float4*)acc)[q];
  }
}

// ============ prim conv: [B,256,20,20] -> partial [B,256,6,6] (K-quarter) ===
// grid: nimg*4 (imgl = bid>>2, kq = bid&3). block 128 = 64 ocg x 2 rowg.
// thread: 4 oc x 18 px (3 rows x 6). 4 partial buffers summed in k_squash.
#define W2PAD 268   // %32==12 -> staging-write conflicts ~4-way only; 16B aligned
#define PQ_STRIDE 2359296
__global__ __launch_bounds__(128, 2) void k_conv2(const float* __restrict__ h,
                                                  const float* __restrict__ w,
                                                  const float* __restrict__ bias,
                                                  float* __restrict__ pout,
                                                  int c0) {
  const int imgl = blockIdx.x >> 2, kq = blockIdx.x & 3;
  __shared__ float hs[400];
  __shared__ float wT[27 * W2PAD];                  // k-major, oc contiguous
  const int t = threadIdx.x;
  const int ocg = t & 63, rowg = t >> 6;
  const int oc0 = ocg * 4;
  float acc[4][18];
  if (kq == 0) {
    const float4 bv = *(const float4*)&bias[oc0];
#pragma unroll
    for (int p = 0; p < 18; p++) {
      acc[0][p] = bv.x; acc[1][p] = bv.y; acc[2][p] = bv.z; acc[3][p] = bv.w;
    }
  } else {
#pragma unroll
    for (int c = 0; c < 4; c++)
#pragma unroll
      for (int p = 0; p < 18; p++) acc[c][p] = 0.f;
  }
  const float* hb = h + (size_t)imgl * 102400;
  const int ic0 = kq * 64;
#pragma unroll 1
  for (int ic = ic0; ic < ic0 + 64; ic++) {
    const float* hsrc = hb + (size_t)ic * 400;
    const float* wic = w + (size_t)ic * 81;
#pragma unroll 1
    for (int ph = 0; ph < 3; ph++) {                // ky thirds: 27 k each
      __syncthreads();
      if (ph == 0)
        for (int i = t; i < 100; i += 128) ((float4*)hs)[i] = ((const float4*)hsrc)[i];
      const float* wsrc = wic + ph * 27;
#pragma unroll 1
      for (int idx = t; idx < 27 * 256; idx += 128) {
        const int oc = idx / 27, kk = idx - oc * 27;   // coalesced global read
        wT[kk * W2PAD + oc] = wsrc[(size_t)oc * 20736 + kk];
      }
      __syncthreads();
#pragma unroll
      for (int kyl = 0; kyl < 3; kyl++) {
        float4 wv[9];
#pragma unroll
        for (int kx = 0; kx < 9; kx++)
          wv[kx] = *(const float4*)&wT[(kyl * 9 + kx) * W2PAD + oc0];  // conflict-free
#pragma unroll
        for (int rr = 0; rr < 3; rr++) {
          const int oy = rowg * 3 + rr;
          const int y = 2 * oy + ph * 3 + kyl;
          const float* hrow = &hs[y * 20];          // broadcast (wave-uniform)
          float xr[19];
#pragma unroll
          for (int q = 0; q < 4; q++) ((float4*)xr)[q] = ((const float4*)hrow)[q];
          xr[16] = hrow[16]; xr[17] = hrow[17]; xr[18] = hrow[18];
#pragma unroll
          for (int kx = 0; kx < 9; kx++) {
#pragma unroll
            for (int px = 0; px < 6; px++) {
              const float xv = xr[2 * px + kx];
              const int ap = rr * 6 + px;
              acc[0][ap] = fmaf(wv[kx].x, xv, acc[0][ap]);
              acc[1][ap] = fmaf(wv[kx].y, xv, acc[1][ap]);
              acc[2][ap] = fmaf(wv[kx].z, xv, acc[2][ap]);
              acc[3][ap] = fmaf(wv[kx].w, xv, acc[3][ap]);
            }
          }
        }
      }
    }
  }
  const int img = c0 + imgl;
  float* pq = pout + (size_t)kq * PQ_STRIDE;
#pragma unroll
  for (int c = 0; c < 4; c++) {
    float* pb = pq + ((size_t)img * 256 + (oc0 + c)) * 36 + rowg * 18;
#pragma unroll
    for (int q = 0; q < 9; q++)
      ((float2*)pb)[q] = make_float2(acc[c][2 * q], acc[c][2 * q + 1]);
  }
}

// ===== squash: sum 4 partials, reshape [B,256,36]->[B,1152,8], squash ======
__global__ __launch_bounds__(256) void k_squash(const float* __restrict__ pq,
                                                float* __restrict__ u) {
  const int gid = blockIdx.x * 256 + threadIdx.x;   // b*1152 + i
  const int b = gid / 1152, i = gid - b * 1152;
  const int cp = i / 36, px = i - cp * 36;
  float s[8];
#pragma unroll
  for (int d = 0; d < 8; d++) {
    const size_t idx = ((size_t)b * 256 + (d * 32 + cp)) * 36 + px;
    s[d] = pq[idx] + pq[PQ_STRIDE + idx] + pq[2 * (size_t)PQ_STRIDE + idx] +
           pq[3 * (size_t)PQ_STRIDE + idx];
  }
  float sq = 0.f;
#pragma unroll
  for (int d = 0; d < 8; d++) sq = fmaf(s[d], s[d], sq);
  const float scale = sq / ((1.f + sq) * sqrtf(sq));
  float o[8];
#pragma unroll
  for (int d = 0; d < 8; d++) o[d] = s[d] * scale;
  float* ub = u + (size_t)gid * 8;
  ((float4*)ub)[0] = ((float4*)o)[0];
  ((float4*)ub)[1] = ((float4*)o)[1];
}

// ======================= routing by agreement (per o,b block) ==============
__device__ __forceinline__ float wsum(float v) {
#pragma unroll
  for (int o = 32; o > 0; o >>= 1) v += __shfl_xor(v, o, 64);
  return v;
}
__device__ __forceinline__ float wmaxr(float v) {
#pragma unroll
  for (int o = 32; o > 0; o >>= 1) v = fmaxf(v, __shfl_xor(v, o, 64));
  return v;
}

__global__ __launch_bounds__(256) void k_route(const float* __restrict__ u,
                                               const float* __restrict__ rw,
                                               float* __restrict__ vecs) {
  const int o = blockIdx.x >> 8, b = blockIdx.x & 255;
  __shared__ float us[9216];
  __shared__ float red[4 * 17];
  __shared__ float redm[4];
  const int t = threadIdx.x;
  const int wave = t >> 6, lane = t & 63;
  {
    const float4* ub = (const float4*)(u + (size_t)b * 9216);
    for (int i = t; i < 2304; i += 256) ((float4*)us)[i] = ub[i];
  }
  __syncthreads();
  // caps: i = t + ci*256; ci==4 valid only for t<128 (4*256+128 = 1152)
  float pri[5][16];
  const float* rwo = rw + (size_t)o * 147456;
#pragma unroll
  for (int ci = 0; ci < 5; ci++) {
    const bool valid = (ci < 4) || (t < 128);
    const int i = valid ? (t + ci * 256) : 0;
    const float* rwi = rwo + (size_t)i * 128;
    float a[16];
#pragma unroll
    for (int d = 0; d < 16; d++) a[d] = 0.f;
#pragma unroll
    for (int c = 0; c < 8; c++) {
      const float uv = us[i * 8 + c];
      const float4* r4 = (const float4*)(rwi + c * 16);
      const float4 p0 = r4[0], p1 = r4[1], p2 = r4[2], p3 = r4[3];
      a[0] = fmaf(uv, p0.x, a[0]);  a[1] = fmaf(uv, p0.y, a[1]);
      a[2] = fmaf(uv, p0.z, a[2]);  a[3] = fmaf(uv, p0.w, a[3]);
      a[4] = fmaf(uv, p1.x, a[4]);  a[5] = fmaf(uv, p1.y, a[5]);
      a[6] = fmaf(uv, p1.z, a[6]);  a[7] = fmaf(uv, p1.w, a[7]);
      a[8] = fmaf(uv, p2.x, a[8]);  a[9] = fmaf(uv, p2.y, a[9]);
      a[10] = fmaf(uv, p2.z, a[10]); a[11] = fmaf(uv, p2.w, a[11]);
      a[12] = fmaf(uv, p3.x, a[12]); a[13] = fmaf(uv, p3.y, a[13]);
      a[14] = fmaf(uv, p3.z, a[14]); a[15] = fmaf(uv, p3.w, a[15]);
    }
#pragma unroll
    for (int d = 0; d < 16; d++) pri[ci][d] = valid ? a[d] : 0.f;
  }
  float l[5];
#pragma unroll
  for (int ci = 0; ci < 5; ci++)
    l[ci] = ((ci < 4) || (t < 128)) ? 0.f : -1e30f;  // dummy caps -> exp=0
  float v[16];
#pragma unroll 1
  for (int it = 0; it < 3; it++) {
    float m = l[0];
#pragma unroll
    for (int ci = 1; ci < 5; ci++) m = fmaxf(m, l[ci]);
    m = wmaxr(m);
    if (lane == 0) redm[wave] = m;
    __syncthreads();
    m = fmaxf(fmaxf(redm[0], redm[1]), fmaxf(redm[2], redm[3]));
    float Z = 0.f, S[16];
#pragma unroll
    for (int d = 0; d < 16; d++) S[d] = 0.f;
#pragma unroll
    for (int ci = 0; ci < 5; ci++) {
      const float e = expf(l[ci] - m);
      Z += e;
#pragma unroll
      for (int d = 0; d < 16; d++) S[d] = fmaf(e, pri[ci][d], S[d]);
    }
    Z = wsum(Z);
#pragma unroll
    for (int d = 0; d < 16; d++) S[d] = wsum(S[d]);
    __syncthreads();
    if (lane == 0) {
      red[wave * 17] = Z;
#pragma unroll
      for (int d = 0; d < 16; d++) red[wave * 17 + 1 + d] = S[d];
    }
    __syncthreads();
    const float Zt = red[0] + red[17] + red[34] + red[51];
    float sv[16], sq = 0.f;
#pragma unroll
    for (int d = 0; d < 16; d++) {
      const float sd = (red[1 + d] + red[18 + d] + red[35 + d] + red[52 + d]) / Zt;
      sv[d] = sd;
      sq = fmaf(sd, sd, sq);
    }
    const float scale = sq / ((1.f + sq) * sqrtf(sq));
#pragma unroll
    for (int d = 0; d < 16; d++) v[d] = scale * sv[d];
    if (it < 2) {
#pragma unroll
      for (int ci = 0; ci < 5; ci++) {
        float dot = 0.f;
#pragma unroll
        for (int d = 0; d < 16; d++) dot = fmaf(pri[ci][d], v[d], dot);
        l[ci] += dot;
      }
    }
  }
  if (t == 0) {
    float* vb = vecs + ((size_t)b * 10 + o) * 16;
#pragma unroll
    for (int d = 0; d < 16; d++) vb[d] = v[d];
  }
}

// =============== classes softmax + argmax + selected-vector ================
__global__ __launch_bounds__(64) void k_cls(const float* __restrict__ vecs,
                                            float* __restrict__ out,
                                            float* __restrict__ selvec,
                                            int* __restrict__ amv) {
  const int b = blockIdx.x * 64 + threadIdx.x;
  const float* vb = vecs + (size_t)b * 160;
  float n[10];
#pragma unroll
  for (int o = 0; o < 10; o++) {
    float sq = 0.f;
#pragma unroll
    for (int d = 0; d < 16; d++) { const float xv = vb[o * 16 + d]; sq = fmaf(xv, xv, sq); }
    n[o] = sqrtf(sq);
  }
  float m = n[0];
#pragma unroll
  for (int o = 1; o < 10; o++) m = fmaxf(m, n[o]);
  float e[10], Z = 0.f;
#pragma unroll
  for (int o = 0; o < 10; o++) { e[o] = expf(n[o] - m); Z += e[o]; }
  const float inv = 1.f / Z;
  float cls[10];
#pragma unroll
  for (int o = 0; o < 10; o++) {
    cls[o] = e[o] * inv;
    out[(size_t)b * 10 + o] = cls[o];
  }
  int am = 0;
  float best = cls[0];
#pragma unroll
  for (int o = 1; o < 10; o++)
    if (cls[o] > best) { best = cls[o]; am = o; }   // strict > = first-max (jnp.argmax)
  amv[b] = am;
#pragma unroll
  for (int d = 0; d < 16; d++) selvec[(size_t)b * 16 + d] = vb[am * 16 + d];
}

// ============================= decoder =====================================
__global__ __launch_bounds__(512) void k_dec1(const float* __restrict__ selvec,
                                              const int* __restrict__ amv,
                                              const float* __restrict__ w1,
                                              const float* __restrict__ b1,
                                              float* __restrict__ h1) {
  const int b = blockIdx.x, t = threadIdx.x;
  __shared__ float sv[16];
  __shared__ int ams;
  if (t < 16) sv[t] = selvec[(size_t)b * 16 + t];
  if (t == 0) ams = amv[b];
  __syncthreads();
  const float* wrow = w1 + (size_t)ams * 16 * 512;
  float acc = b1[t];
#pragma unroll
  for (int d = 0; d < 16; d++) acc = fmaf(sv[d], wrow[d * 512 + t], acc);
  h1[(size_t)b * 512 + t] = fmaxf(acc, 0.f);
}

__global__ __launch_bounds__(128) void k_dec2(const float* __restrict__ h1,
                                              const float* __restrict__ w2,
                                              const float* __restrict__ b2,
                                              float* __restrict__ h2) {
  const int nc = blockIdx.x >> 5, bg = blockIdx.x & 31;
  const int t = threadIdx.x;
  const int n = nc * 128 + t;
  const int bs = bg * 8;
  __shared__ float h1s[8 * 512];
  {
    const float4* src = (const float4*)(h1 + (size_t)bs * 512);
    for (int i = t; i < 1024; i += 128) ((float4*)h1s)[i] = src[i];
  }
  __syncthreads();
  float acc[8];
  const float bb = b2[n];
#pragma unroll
  for (int j = 0; j < 8; j++) acc[j] = bb;
#pragma unroll 1
  for (int k = 0; k < 512; k += 4) {
    float wq[4];
#pragma unroll
    for (int q = 0; q < 4; q++) wq[q] = w2[(size_t)(k + q) * 1024 + n];
#pragma unroll
    for (int j = 0; j < 8; j++) {
      const float4 hv = *(const float4*)&h1s[j * 512 + k];
      acc[j] = fmaf(hv.x, wq[0], acc[j]);
      acc[j] = fmaf(hv.y, wq[1], acc[j]);
      acc[j] = fmaf(hv.z, wq[2], acc[j]);
      acc[j] = fmaf(hv.w, wq[3], acc[j]);
    }
  }
#pragma unroll
  for (int j = 0; j < 8; j++) h2[(size_t)(bs + j) * 1024 + n] = fmaxf(acc[j], 0.f);
}

__global__ __launch_bounds__(128) void k_dec3(const float* __restrict__ h2,
                                              const float* __restrict__ w3,
                                              const float* __restrict__ b3,
                                              float* __restrict__ out) {
  const int nc = blockIdx.x >> 5, bg = blockIdx.x & 31;   // grid 7*32
  const int t = threadIdx.x;
  const int bs = bg * 8;
  __shared__ float h2s[8 * 1024];
  {
    const float4* src = (const float4*)(h2 + (size_t)bs * 1024);
    for (int i = t; i < 2048; i += 128) ((float4*)h2s)[i] = src[i];
  }
  __syncthreads();
  if (t >= 112) return;                                   // no barriers after
  const int n = nc * 112 + t;
  float acc[8];
  const float bb = b3[n];
#pragma unroll
  for (int j = 0; j < 8; j++) acc[j] = bb;
#pragma unroll 1
  for (int k = 0; k < 1024; k += 4) {
    float wq[4];
#pragma unroll
    for (int q = 0; q < 4; q++) wq[q] = w3[(size_t)(k + q) * 784 + n];
#pragma unroll
    for (int j = 0; j < 8; j++) {
      const float4 hv = *(const float4*)&h2s[j * 1024 + k];
      acc[j] = fmaf(hv.x, wq[0], acc[j]);
      acc[j] = fmaf(hv.y, wq[1], acc[j]);
      acc[j] = fmaf(hv.z, wq[2], acc[j]);
      acc[j] = fmaf(hv.w, wq[3], acc[j]);
    }
  }
#pragma unroll
  for (int j = 0; j < 8; j++)
    out[(size_t)(bs + j) * 784 + n] = 1.f / (1.f + expf(-acc[j]));
}

// ============================= launcher ====================================
extern "C" void kernel_launch(void* const* d_in, const int* in_sizes, int n_in,
                              void* d_out, int out_size, void* d_ws, size_t ws_size,
                              hipStream_t stream) {
  const float* x   = (const float*)d_in[0];
  const float* c1w = (const float*)d_in[1];
  const float* c1b = (const float*)d_in[2];
  const float* pw  = (const float*)d_in[3];
  const float* pb  = (const float*)d_in[4];
  const float* rw  = (const float*)d_in[5];
  const float* w1  = (const float*)d_in[6];
  const float* b1  = (const float*)d_in[7];
  const float* w2  = (const float*)d_in[8];
  const float* b2  = (const float*)d_in[9];
  const float* w3  = (const float*)d_in[10];
  const float* b3  = (const float*)d_in[11];
  float* out = (float*)d_out;
  float* ws = (float*)d_ws;

  const size_t PQ = 2359296;  // 256*256*36
  const size_t fixed_f = 4 * PQ + PQ + 40960 + 4096 + 256 + 131072 + 262144;
  int chunk = 256;            // images whose conv1 output fits in workspace
  while (chunk > 8 && (fixed_f + (size_t)chunk * 102400) * 4 > ws_size) chunk >>= 1;

  float* h_buf = ws;                                // chunk*102400 floats
  float* pq    = ws + (size_t)chunk * 102400;       // 4 partial conv2 buffers
  float* u     = pq + 4 * PQ;                       // [B,1152,8]
  float* vecs  = u + PQ;                            // [B,10,16]
  float* sel   = vecs + 40960;                      // [B,16]
  int*   amv   = (int*)(sel + 4096);                // [B]
  float* h1    = sel + 4096 + 256;                  // [B,512]
  float* h2    = h1 + 131072;                       // [B,1024]

  for (int c0 = 0; c0 < 256; c0 += chunk) {
    k_conv1<<<dim3(chunk * 4), dim3(256), 0, stream>>>(x + (size_t)c0 * 784, c1w, c1b, h_buf);
    k_conv2<<<dim3(chunk * 4), dim3(128), 0, stream>>>(h_buf, pw, pb, pq, c0);
  }
  k_squash<<<dim3(1152), dim3(256), 0, stream>>>(pq, u);
  k_route<<<dim3(2560), dim3(256), 0, stream>>>(u, rw, vecs);
  k_cls<<<dim3(4), dim3(64), 0, stream>>>(vecs, out, sel, amv);
  k_dec1<<<dim3(256), dim3(512), 0, stream>>>(sel, amv, w1, b1, h1);
  k_dec2<<<dim3(256), dim3(128), 0, stream>>>(h1, w2, b2, h2);
  k_dec3<<<dim3(224), dim3(128), 0, stream>>>(h2, w3, b3, out + 2560);
}

// Round 2
// 2199.632 us; speedup vs baseline: 1.6566x; 1.6566x over previous
//
#include <hip/hip_runtime.h>
#include <math.h>

// ---------------------------------------------------------------------------
// CapsNet forward, fp32 everywhere (no fp32 MFMA on CDNA4 -> vector ALU).
// R2: k_conv2 rewritten spill-free (acc 36 regs, VGPR<=128, 4 blocks/CU) +
// one-time weight repack [oc][ic][k] -> [ic][k][oc] for coalesced,
// conflict-free staging.
// ---------------------------------------------------------------------------

// ======================= conv1: [B,1,28,28] -> [B,256,20,20] relu ==========
__global__ __launch_bounds__(256) void k_conv1(const float* __restrict__ x,
                                               const float* __restrict__ w,
                                               const float* __restrict__ bias,
                                               float* __restrict__ h) {
  const int bid = blockIdx.x;
  const int img = bid >> 2, ocq = bid & 3;          // 64 oc per block
  __shared__ float xs[784];
  __shared__ float ws[64 * 81];
  const int t = threadIdx.x;
  const float4* xg = (const float4*)(x + (size_t)img * 784);
  if (t < 196) ((float4*)xs)[t] = xg[t];
  const float4* wg = (const float4*)(w + (size_t)ocq * 64 * 81);
  for (int i = t; i < 1296; i += 256) ((float4*)ws)[i] = wg[i];
  __syncthreads();
  const int ocl = t & 63, rowg = t >> 6;            // wave-uniform row
  const int oc = ocq * 64 + ocl;
  const float bv = bias[oc];
  float* hb = h + ((size_t)img * 256 + oc) * 400;
#pragma unroll 1
  for (int r = rowg; r < 20; r += 4) {
    float acc[20];
#pragma unroll
    for (int p = 0; p < 20; p++) acc[p] = bv;
#pragma unroll
    for (int ky = 0; ky < 9; ky++) {
      float xr[28];
      const float* xrow = &xs[(r + ky) * 28];       // broadcast reads (free)
#pragma unroll
      for (int q = 0; q < 7; q++) ((float4*)xr)[q] = ((const float4*)xrow)[q];
      float wr[9];
#pragma unroll
      for (int i = 0; i < 9; i++) wr[i] = ws[ocl * 81 + ky * 9 + i];
#pragma unroll
      for (int kx = 0; kx < 9; kx++)
#pragma unroll
        for (int p = 0; p < 20; p++)
          acc[p] = fmaf(wr[kx], xr[p + kx], acc[p]);
    }
#pragma unroll
    for (int p = 0; p < 20; p++) acc[p] = fmaxf(acc[p], 0.f);
#pragma unroll
    for (int q = 0; q < 5; q++) ((float4*)(hb + r * 20))[q] = ((float4*)acc)[q];
  }
}

// ====== weight repack: w[oc][ic][81] -> wR[ic][81][oc]  (runs every launch) =
__global__ __launch_bounds__(256) void k_repack(const float* __restrict__ w,
                                                float* __restrict__ wR) {
  const int ic = blockIdx.x >> 2, ocq = blockIdx.x & 3;
  __shared__ float tile[81 * 65];                   // pad 65: conflict-free
  const int t = threadIdx.x;
  for (int i = t; i < 81 * 64; i += 256) {
    const int ocl = i / 81, k = i - ocl * 81;       // coalesced-ish 81-chunks
    tile[k * 65 + ocl] = w[((size_t)(ocq * 64 + ocl) * 256 + ic) * 81 + k];
  }
  __syncthreads();
  const int ocl = t & 63, kr = t >> 6;
  for (int k = kr; k < 81; k += 4)                  // 256 B coalesced writes
    wR[((size_t)ic * 81 + k) * 256 + ocq * 64 + ocl] = tile[k * 65 + ocl];
}

// ============ prim conv: [B,256,20,20] -> partial [B,256,6,6] (K-quarter) ===
// grid: nimg*4 (imgl=bid>>2, kq=bid&3). block 256 = 128 ocg(2 oc) x 2 rowg(3 rows).
// acc[2][18] = 36 regs -> no spill. wR layout gives conflict-free staging.
#define PQ_STRIDE 2359296
__global__ __launch_bounds__(256, 4) void k_conv2(const float* __restrict__ h,
                                                  const float* __restrict__ wR,
                                                  const float* __restrict__ bias,
                                                  float* __restrict__ pout,
                                                  int c0) {
  const int imgl = blockIdx.x >> 2, kq = blockIdx.x & 3;
  __shared__ float hs[400];
  __shared__ float wT[27 * 256];                    // [k][oc], no pad needed
  const int t = threadIdx.x;
  const int ocg = t & 127, rowg = t >> 7;           // rows wave-uniform
  const int wave = t >> 6, lane = t & 63;
  const int oc2 = ocg * 2;
  float acc[2][18];
  if (kq == 0) {
    const float2 bv = *(const float2*)&bias[oc2];
#pragma unroll
    for (int p = 0; p < 18; p++) { acc[0][p] = bv.x; acc[1][p] = bv.y; }
  } else {
#pragma unroll
    for (int p = 0; p < 18; p++) { acc[0][p] = 0.f; acc[1][p] = 0.f; }
  }
  const float* hb = h + (size_t)imgl * 102400;
  const int ic0 = kq * 64;
#pragma unroll 1
  for (int ic = ic0; ic < ic0 + 64; ic++) {
#pragma unroll 1
    for (int ph = 0; ph < 3; ph++) {                // 27 k-taps per stage
      __syncthreads();
      if (ph == 0 && t < 100)
        ((float4*)hs)[t] = ((const float4*)(hb + (size_t)ic * 400))[t];
      const float4* wsrc = (const float4*)(wR + ((size_t)ic * 81 + ph * 27) * 256);
#pragma unroll 1
      for (int c = wave; c < 27; c += 4)            // coalesced, conflict-free
        ((float4*)&wT[c * 256])[lane] = wsrc[c * 64 + lane];
      __syncthreads();
#pragma unroll
      for (int kyl = 0; kyl < 3; kyl++) {
        float2 wv[9];
#pragma unroll
        for (int kx = 0; kx < 9; kx++)
          wv[kx] = *(const float2*)&wT[(kyl * 9 + kx) * 256 + oc2];
#pragma unroll
        for (int rr = 0; rr < 3; rr++) {
          const int y = (rowg * 3 + rr) * 2 + ph * 3 + kyl;
          const float* hrow = &hs[y * 20];          // wave-uniform: broadcast
          float xr[20];
#pragma unroll
          for (int q = 0; q < 5; q++) ((float4*)xr)[q] = ((const float4*)hrow)[q];
#pragma unroll
          for (int kx = 0; kx < 9; kx++) {
#pragma unroll
            for (int px = 0; px < 6; px++) {
              const float xv = xr[2 * px + kx];
              const int ap = rr * 6 + px;
              acc[0][ap] = fmaf(wv[kx].x, xv, acc[0][ap]);
              acc[1][ap] = fmaf(wv[kx].y, xv, acc[1][ap]);
            }
          }
        }
      }
    }
  }
  const int img = c0 + imgl;
  float* pq = pout + (size_t)kq * PQ_STRIDE;
#pragma unroll
  for (int c = 0; c < 2; c++) {
    float* pb = pq + ((size_t)img * 256 + (oc2 + c)) * 36 + rowg * 18;
#pragma unroll
    for (int q = 0; q < 9; q++)
      ((float2*)pb)[q] = make_float2(acc[c][2 * q], acc[c][2 * q + 1]);
  }
}

// ===== squash: sum 4 partials, reshape [B,256,36]->[B,1152,8], squash ======
__global__ __launch_bounds__(256) void k_squash(const float* __restrict__ pq,
                                                float* __restrict__ u) {
  const int gid = blockIdx.x * 256 + threadIdx.x;   // b*1152 + i
  const int b = gid / 1152, i = gid - b * 1152;
  const int cp = i / 36, px = i - cp * 36;
  float s[8];
#pragma unroll
  for (int d = 0; d < 8; d++) {
    const size_t idx = ((size_t)b * 256 + (d * 32 + cp)) * 36 + px;
    s[d] = pq[idx] + pq[PQ_STRIDE + idx] + pq[2 * (size_t)PQ_STRIDE + idx] +
           pq[3 * (size_t)PQ_STRIDE + idx];
  }
  float sq = 0.f;
#pragma unroll
  for (int d = 0; d < 8; d++) sq = fmaf(s[d], s[d], sq);
  const float scale = sq / ((1.f + sq) * sqrtf(sq));
  float o[8];
#pragma unroll
  for (int d = 0; d < 8; d++) o[d] = s[d] * scale;
  float* ub = u + (size_t)gid * 8;
  ((float4*)ub)[0] = ((float4*)o)[0];
  ((float4*)ub)[1] = ((float4*)o)[1];
}

// ======================= routing by agreement (per o,b block) ==============
__device__ __forceinline__ float wsum(float v) {
#pragma unroll
  for (int o = 32; o > 0; o >>= 1) v += __shfl_xor(v, o, 64);
  return v;
}
__device__ __forceinline__ float wmaxr(float v) {
#pragma unroll
  for (int o = 32; o > 0; o >>= 1) v = fmaxf(v, __shfl_xor(v, o, 64));
  return v;
}

__global__ __launch_bounds__(256) void k_route(const float* __restrict__ u,
                                               const float* __restrict__ rw,
                                               float* __restrict__ vecs) {
  const int o = blockIdx.x >> 8, b = blockIdx.x & 255;
  __shared__ float us[9216];
  __shared__ float red[4 * 17];
  __shared__ float redm[4];
  const int t = threadIdx.x;
  const int wave = t >> 6, lane = t & 63;
  {
    const float4* ub = (const float4*)(u + (size_t)b * 9216);
    for (int i = t; i < 2304; i += 256) ((float4*)us)[i] = ub[i];
  }
  __syncthreads();
  float pri[5][16];
  const float* rwo = rw + (size_t)o * 147456;
#pragma unroll
  for (int ci = 0; ci < 5; ci++) {
    const bool valid = (ci < 4) || (t < 128);
    const int i = valid ? (t + ci * 256) : 0;
    const float* rwi = rwo + (size_t)i * 128;
    float a[16];
#pragma unroll
    for (int d = 0; d < 16; d++) a[d] = 0.f;
#pragma unroll
    for (int c = 0; c < 8; c++) {
      const float uv = us[i * 8 + c];
      const float4* r4 = (const float4*)(rwi + c * 16);
      const float4 p0 = r4[0], p1 = r4[1], p2 = r4[2], p3 = r4[3];
      a[0] = fmaf(uv, p0.x, a[0]);  a[1] = fmaf(uv, p0.y, a[1]);
      a[2] = fmaf(uv, p0.z, a[2]);  a[3] = fmaf(uv, p0.w, a[3]);
      a[4] = fmaf(uv, p1.x, a[4]);  a[5] = fmaf(uv, p1.y, a[5]);
      a[6] = fmaf(uv, p1.z, a[6]);  a[7] = fmaf(uv, p1.w, a[7]);
      a[8] = fmaf(uv, p2.x, a[8]);  a[9] = fmaf(uv, p2.y, a[9]);
      a[10] = fmaf(uv, p2.z, a[10]); a[11] = fmaf(uv, p2.w, a[11]);
      a[12] = fmaf(uv, p3.x, a[12]); a[13] = fmaf(uv, p3.y, a[13]);
      a[14] = fmaf(uv, p3.z, a[14]); a[15] = fmaf(uv, p3.w, a[15]);
    }
#pragma unroll
    for (int d = 0; d < 16; d++) pri[ci][d] = valid ? a[d] : 0.f;
  }
  float l[5];
#pragma unroll
  for (int ci = 0; ci < 5; ci++)
    l[ci] = ((ci < 4) || (t < 128)) ? 0.f : -1e30f;  // dummy caps -> exp=0
  float v[16];
#pragma unroll 1
  for (int it = 0; it < 3; it++) {
    float m = l[0];
#pragma unroll
    for (int ci = 1; ci < 5; ci++) m = fmaxf(m, l[ci]);
    m = wmaxr(m);
    if (lane == 0) redm[wave] = m;
    __syncthreads();
    m = fmaxf(fmaxf(redm[0], redm[1]), fmaxf(redm[2], redm[3]));
    float Z = 0.f, S[16];
#pragma unroll
    for (int d = 0; d < 16; d++) S[d] = 0.f;
#pragma unroll
    for (int ci = 0; ci < 5; ci++) {
      const float e = expf(l[ci] - m);
      Z += e;
#pragma unroll
      for (int d = 0; d < 16; d++) S[d] = fmaf(e, pri[ci][d], S[d]);
    }
    Z = wsum(Z);
#pragma unroll
    for (int d = 0; d < 16; d++) S[d] = wsum(S[d]);
    __syncthreads();
    if (lane == 0) {
      red[wave * 17] = Z;
#pragma unroll
      for (int d = 0; d < 16; d++) red[wave * 17 + 1 + d] = S[d];
    }
    __syncthreads();
    const float Zt = red[0] + red[17] + red[34] + red[51];
    float sv[16], sq = 0.f;
#pragma unroll
    for (int d = 0; d < 16; d++) {
      const float sd = (red[1 + d] + red[18 + d] + red[35 + d] + red[52 + d]) / Zt;
      sv[d] = sd;
      sq = fmaf(sd, sd, sq);
    }
    const float scale = sq / ((1.f + sq) * sqrtf(sq));
#pragma unroll
    for (int d = 0; d < 16; d++) v[d] = scale * sv[d];
    if (it < 2) {
#pragma unroll
      for (int ci = 0; ci < 5; ci++) {
        float dot = 0.f;
#pragma unroll
        for (int d = 0; d < 16; d++) dot = fmaf(pri[ci][d], v[d], dot);
        l[ci] += dot;
      }
    }
  }
  if (t == 0) {
    float* vb = vecs + ((size_t)b * 10 + o) * 16;
#pragma unroll
    for (int d = 0; d < 16; d++) vb[d] = v[d];
  }
}

// =============== classes softmax + argmax + selected-vector ================
__global__ __launch_bounds__(64) void k_cls(const float* __restrict__ vecs,
                                            float* __restrict__ out,
                                            float* __restrict__ selvec,
                                            int* __restrict__ amv) {
  const int b = blockIdx.x * 64 + threadIdx.x;
  const float* vb = vecs + (size_t)b * 160;
  float n[10];
#pragma unroll
  for (int o = 0; o < 10; o++) {
    float sq = 0.f;
#pragma unroll
    for (int d = 0; d < 16; d++) { const float xv = vb[o * 16 + d]; sq = fmaf(xv, xv, sq); }
    n[o] = sqrtf(sq);
  }
  float m = n[0];
#pragma unroll
  for (int o = 1; o < 10; o++) m = fmaxf(m, n[o]);
  float e[10], Z = 0.f;
#pragma unroll
  for (int o = 0; o < 10; o++) { e[o] = expf(n[o] - m); Z += e[o]; }
  const float inv = 1.f / Z;
  float cls[10];
#pragma unroll
  for (int o = 0; o < 10; o++) {
    cls[o] = e[o] * inv;
    out[(size_t)b * 10 + o] = cls[o];
  }
  int am = 0;
  float best = cls[0];
#pragma unroll
  for (int o = 1; o < 10; o++)
    if (cls[o] > best) { best = cls[o]; am = o; }   // strict > = first-max (jnp.argmax)
  amv[b] = am;
#pragma unroll
  for (int d = 0; d < 16; d++) selvec[(size_t)b * 16 + d] = vb[am * 16 + d];
}

// ============================= decoder =====================================
__global__ __launch_bounds__(512) void k_dec1(const float* __restrict__ selvec,
                                              const int* __restrict__ amv,
                                              const float* __restrict__ w1,
                                              const float* __restrict__ b1,
                                              float* __restrict__ h1) {
  const int b = blockIdx.x, t = threadIdx.x;
  __shared__ float sv[16];
  __shared__ int ams;
  if (t < 16) sv[t] = selvec[(size_t)b * 16 + t];
  if (t == 0) ams = amv[b];
  __syncthreads();
  const float* wrow = w1 + (size_t)ams * 16 * 512;
  float acc = b1[t];
#pragma unroll
  for (int d = 0; d < 16; d++) acc = fmaf(sv[d], wrow[d * 512 + t], acc);
  h1[(size_t)b * 512 + t] = fmaxf(acc, 0.f);
}

__global__ __launch_bounds__(128) void k_dec2(const float* __restrict__ h1,
                                              const float* __restrict__ w2,
                                              const float* __restrict__ b2,
                                              float* __restrict__ h2) {
  const int nc = blockIdx.x >> 5, bg = blockIdx.x & 31;
  const int t = threadIdx.x;
  const int n = nc * 128 + t;
  const int bs = bg * 8;
  __shared__ float h1s[8 * 512];
  {
    const float4* src = (const float4*)(h1 + (size_t)bs * 512);
    for (int i = t; i < 1024; i += 128) ((float4*)h1s)[i] = src[i];
  }
  __syncthreads();
  float acc[8];
  const float bb = b2[n];
#pragma unroll
  for (int j = 0; j < 8; j++) acc[j] = bb;
#pragma unroll 1
  for (int k = 0; k < 512; k += 4) {
    float wq[4];
#pragma unroll
    for (int q = 0; q < 4; q++) wq[q] = w2[(size_t)(k + q) * 1024 + n];
#pragma unroll
    for (int j = 0; j < 8; j++) {
      const float4 hv = *(const float4*)&h1s[j * 512 + k];
      acc[j] = fmaf(hv.x, wq[0], acc[j]);
      acc[j] = fmaf(hv.y, wq[1], acc[j]);
      acc[j] = fmaf(hv.z, wq[2], acc[j]);
      acc[j] = fmaf(hv.w, wq[3], acc[j]);
    }
  }
#pragma unroll
  for (int j = 0; j < 8; j++) h2[(size_t)(bs + j) * 1024 + n] = fmaxf(acc[j], 0.f);
}

__global__ __launch_bounds__(128) void k_dec3(const float* __restrict__ h2,
                                              const float* __restrict__ w3,
                                              const float* __restrict__ b3,
                                              float* __restrict__ out) {
  const int nc = blockIdx.x >> 5, bg = blockIdx.x & 31;   // grid 7*32
  const int t = threadIdx.x;
  const int bs = bg * 8;
  __shared__ float h2s[8 * 1024];
  {
    const float4* src = (const float4*)(h2 + (size_t)bs * 1024);
    for (int i = t; i < 2048; i += 128) ((float4*)h2s)[i] = src[i];
  }
  __syncthreads();
  if (t >= 112) return;                                   // no barriers after
  const int n = nc * 112 + t;
  float acc[8];
  const float bb = b3[n];
#pragma unroll
  for (int j = 0; j < 8; j++) acc[j] = bb;
#pragma unroll 1
  for (int k = 0; k < 1024; k += 4) {
    float wq[4];
#pragma unroll
    for (int q = 0; q < 4; q++) wq[q] = w3[(size_t)(k + q) * 784 + n];
#pragma unroll
    for (int j = 0; j < 8; j++) {
      const float4 hv = *(const float4*)&h2s[j * 1024 + k];
      acc[j] = fmaf(hv.x, wq[0], acc[j]);
      acc[j] = fmaf(hv.y, wq[1], acc[j]);
      acc[j] = fmaf(hv.z, wq[2], acc[j]);
      acc[j] = fmaf(hv.w, wq[3], acc[j]);
    }
  }
#pragma unroll
  for (int j = 0; j < 8; j++)
    out[(size_t)(bs + j) * 784 + n] = 1.f / (1.f + expf(-acc[j]));
}

// ============================= launcher ====================================
extern "C" void kernel_launch(void* const* d_in, const int* in_sizes, int n_in,
                              void* d_out, int out_size, void* d_ws, size_t ws_size,
                              hipStream_t stream) {
  const float* x   = (const float*)d_in[0];
  const float* c1w = (const float*)d_in[1];
  const float* c1b = (const float*)d_in[2];
  const float* pw  = (const float*)d_in[3];
  const float* pb  = (const float*)d_in[4];
  const float* rw  = (const float*)d_in[5];
  const float* w1  = (const float*)d_in[6];
  const float* b1  = (const float*)d_in[7];
  const float* w2  = (const float*)d_in[8];
  const float* b2  = (const float*)d_in[9];
  const float* w3  = (const float*)d_in[10];
  const float* b3  = (const float*)d_in[11];
  float* out = (float*)d_out;
  float* ws = (float*)d_ws;

  const size_t PQ = 2359296;  // 256*256*36
  const size_t WRF = 256 * 81 * 256;  // repacked prim weights: 5.3M floats
  const size_t fixed_f = WRF + 4 * PQ + PQ + 40960 + 4096 + 256 + 131072 + 262144;
  int chunk = 256;            // images whose conv1 output fits in workspace
  while (chunk > 8 && (fixed_f + (size_t)chunk * 102400) * 4 > ws_size) chunk >>= 1;

  float* wRp   = ws;                                // [ic][81][oc]
  float* h_buf = wRp + WRF;                         // chunk*102400 floats
  float* pq    = h_buf + (size_t)chunk * 102400;    // 4 partial conv2 buffers
  float* u     = pq + 4 * PQ;                       // [B,1152,8]
  float* vecs  = u + PQ;                            // [B,10,16]
  float* sel   = vecs + 40960;                      // [B,16]
  int*   amv   = (int*)(sel + 4096);                // [B]
  float* h1    = sel + 4096 + 256;                  // [B,512]
  float* h2    = h1 + 131072;                       // [B,1024]

  k_repack<<<dim3(1024), dim3(256), 0, stream>>>(pw, wRp);
  for (int c0 = 0; c0 < 256; c0 += chunk) {
    k_conv1<<<dim3(chunk * 4), dim3(256), 0, stream>>>(x + (size_t)c0 * 784, c1w, c1b, h_buf);
    k_conv2<<<dim3(chunk * 4), dim3(256), 0, stream>>>(h_buf, wRp, pb, pq, c0);
  }
  k_squash<<<dim3(1152), dim3(256), 0, stream>>>(pq, u);
  k_route<<<dim3(2560), dim3(256), 0, stream>>>(u, rw, vecs);
  k_cls<<<dim3(4), dim3(64), 0, stream>>>(vecs, out, sel, amv);
  k_dec1<<<dim3(256), dim3(512), 0, stream>>>(sel, amv, w1, b1, h1);
  k_dec2<<<dim3(256), dim3(128), 0, stream>>>(h1, w2, b2, h2);
  k_dec3<<<dim3(224), dim3(128), 0, stream>>>(h2, w3, b3, out + 2560);
}